// Round 1
// baseline (3172.398 us; speedup 1.0000x reference)
//
#include <hip/hip_runtime.h>
#include <cstdint>

// ---------------- problem constants ----------------
#define BB   128
#define TT   100
#define HID  512

typedef __attribute__((ext_vector_type(4))) float f32x4;
typedef __attribute__((ext_vector_type(8))) short short8;
typedef __attribute__((ext_vector_type(4))) short short4_t;

__device__ __forceinline__ short f2bf(float x) {            // RNE fp32 -> bf16
  unsigned u = __float_as_uint(x);
  unsigned r = (u + 0x7fffu + ((u >> 16) & 1u)) >> 16;
  return (short)r;
}
__device__ __forceinline__ float bf2f(short s) {
  return __uint_as_float(((unsigned)(unsigned short)s) << 16);
}

// ==================== encoder ====================

// conv1: in [128,3,72,72], w [64,3,5,5], stride 3 pad 2 -> out [128,64,24,24], ReLU
__global__ __launch_bounds__(256) void conv1_k(const float* __restrict__ in,
                                               const float* __restrict__ w,
                                               const float* __restrict__ bias,
                                               float* __restrict__ out) {
  __shared__ float ws[64 * 75];
  for (int i = threadIdx.x; i < 64 * 75; i += 256) ws[i] = w[i];
  __syncthreads();
  int tid = blockIdx.x * 256 + threadIdx.x;          // exactly 128*64*576
  int ox = tid % 24, oy = (tid / 24) % 24, oc = (tid / 576) % 64, b = tid / 36864;
  const float* ip = in + (long)b * 3 * 5184;
  const float* wp = ws + oc * 75;
  float s = bias[oc];
  #pragma unroll
  for (int ic = 0; ic < 3; ic++)
    #pragma unroll
    for (int ky = 0; ky < 5; ky++) {
      int iy = oy * 3 + ky - 2;
      if (iy < 0 || iy >= 72) continue;
      #pragma unroll
      for (int kx = 0; kx < 5; kx++) {
        int ix = ox * 3 + kx - 2;
        if (ix < 0 || ix >= 72) continue;
        s += ip[ic * 5184 + iy * 72 + ix] * wp[ic * 25 + ky * 5 + kx];
      }
    }
  out[tid] = fmaxf(s, 0.f);
}

// 3x3 stride-3 pad-2 conv, ReLU. block = (b, oy); threads = OC*OW
template <int IC, int IH, int IW, int OC, int OH, int OW>
__global__ void convs3(const float* __restrict__ in, const float* __restrict__ w,
                       const float* __restrict__ bias, float* __restrict__ out) {
  const int b = blockIdx.x / OH, oy = blockIdx.x % OH;
  __shared__ float in_s[8][3][IW];
  __shared__ float w_s[OC][8][9];
  const int tid = threadIdx.x;
  const int oc = tid / OW, ox = tid % OW;
  float s = bias[oc];
  for (int cc = 0; cc < IC; cc += 8) {
    __syncthreads();
    for (int i = tid; i < 8 * 3 * IW; i += OC * OW) {
      int ic = i / (3 * IW), r = (i / IW) % 3, x = i % IW;
      int iy = oy * 3 - 2 + r;
      in_s[ic][r][x] = (iy >= 0 && iy < IH)
                         ? in[((long)(b * IC + cc + ic) * IH + iy) * IW + x] : 0.f;
    }
    for (int i = tid; i < OC * 8 * 9; i += OC * OW) {
      int o = i / 72, r = i % 72;
      w_s[o][r / 9][r % 9] = w[(long)(o * IC + cc + r / 9) * 9 + r % 9];
    }
    __syncthreads();
    #pragma unroll
    for (int ic = 0; ic < 8; ic++)
      #pragma unroll
      for (int ky = 0; ky < 3; ky++)
        #pragma unroll
        for (int kx = 0; kx < 3; kx++) {
          int ix = ox * 3 + kx - 2;
          if (ix >= 0 && ix < IW) s += in_s[ic][ky][ix] * w_s[oc][ic][ky * 3 + kx];
        }
  }
  out[((long)(b * OC + oc) * OH + oy) * OW + ox] = fmaxf(s, 0.f);
}

// C[128,N] = act(A[128,K] @ W[N,K]^T + b). tile 32x64, 256 thr, 8 rows/thread
template <int K, int N, bool RELU>
__global__ __launch_bounds__(256) void fc_k(const float* __restrict__ A,
                                            const float* __restrict__ W,
                                            const float* __restrict__ bias,
                                            float* __restrict__ C) {
  const int nb = N / 64;
  const int rb = (blockIdx.x / nb) * 32, cb = (blockIdx.x % nb) * 64;
  __shared__ float As[32][65];
  __shared__ float Ws[64][65];
  const int tid = threadIdx.x;
  const int c = tid & 63, rg = tid >> 6;
  float acc[8] = {0.f, 0.f, 0.f, 0.f, 0.f, 0.f, 0.f, 0.f};
  for (int kc = 0; kc < K; kc += 64) {
    for (int i = tid; i < 32 * 64; i += 256)
      As[i >> 6][i & 63] = A[(long)(rb + (i >> 6)) * K + kc + (i & 63)];
    for (int i = tid; i < 64 * 64; i += 256)
      Ws[i >> 6][i & 63] = W[(long)(cb + (i >> 6)) * K + kc + (i & 63)];
    __syncthreads();
    #pragma unroll 8
    for (int k = 0; k < 64; k++) {
      float wv = Ws[c][k];
      #pragma unroll
      for (int i = 0; i < 8; i++) acc[i] += As[rg + 4 * i][k] * wv;
    }
    __syncthreads();
  }
  float bv = bias[cb + c];
  #pragma unroll
  for (int i = 0; i < 8; i++) {
    float v = acc[i] + bv;
    if (RELU) v = fmaxf(v, 0.f);
    C[(long)(rb + rg + 4 * i) * N + cb + c] = v;
  }
}

// ==================== persistent GRU ====================
// grid 256 = 8 batch-groups (contiguous 32-block ranges) x 32 hidden-groups.
// block: 16 batch rows x 16 hidden dims, 192 threads = 3 waves (one per gate).
// w_hh slice held in registers as bf16 hi/lo MFMA B-fragments (bf16x2 split).
// h exchange between the 32 blocks of a group goes through d_out (time-indexed)
// guarded by a monotonic-counter device-scope barrier.
__global__ __launch_bounds__(192, 1) void gru_k(
    const float* __restrict__ actions, const float* __restrict__ w_ih,
    const float* __restrict__ w_hh, const float* __restrict__ b_ih,
    const float* __restrict__ b_hh, const float* __restrict__ h0,
    float* __restrict__ out, float* __restrict__ hT, unsigned* __restrict__ bar) {
  const int bg = blockIdx.x >> 5;   // 0..7
  const int hg = blockIdx.x & 31;   // 0..31
  const int tid = threadIdx.x;
  const int wv = tid >> 6;          // gate: 0=r 1=z 2=n
  const int lane = tid & 63;
  const int n16 = lane & 15;
  const int quad = lane >> 4;

  __shared__ short h_hi[16][520];   // +8 pad: 2-way-max LDS banking for b128 reads
  __shared__ short h_lo[16][520];
  __shared__ float act_s[16][2 * TT];
  __shared__ float gh_s[3][16][17];
  __shared__ float bih_s[48], bhh_s[48], wih0_s[48], wih1_s[48];

  // ---- per-lane w_hh B-fragments (resident in VGPRs for the whole kernel) ----
  short8 whi[16], wlo[16];
  {
    const int grow = wv * HID + hg * 16 + n16;
    const float* wr = w_hh + (long)grow * HID + quad * 8;
    #pragma unroll
    for (int ks = 0; ks < 16; ks++) {
      f32x4 v0 = *(const f32x4*)(wr + ks * 32);
      f32x4 v1 = *(const f32x4*)(wr + ks * 32 + 4);
      short8 hi, lo;
      #pragma unroll
      for (int j = 0; j < 4; j++) {
        short h1 = f2bf(v0[j]); hi[j] = h1;     lo[j] = f2bf(v0[j] - bf2f(h1));
        short h2 = f2bf(v1[j]); hi[j + 4] = h2; lo[j + 4] = f2bf(v1[j] - bf2f(h2));
      }
      whi[ks] = hi; wlo[ks] = lo;
    }
  }
  for (int i = tid; i < 48; i += 192) {
    int row = (i >> 4) * HID + hg * 16 + (i & 15);
    bih_s[i] = b_ih[row];
    bhh_s[i] = b_hh[row];
    wih0_s[i] = w_ih[row * 2];
    wih1_s[i] = w_ih[row * 2 + 1];
  }
  for (int i = tid; i < 16 * 2 * TT; i += 192) {
    int m = i / (2 * TT), r = i % (2 * TT);
    act_s[m][r] = actions[(long)(bg * 16 + m) * (2 * TT) + r];
  }
  // h0 -> LDS (bf16 hi/lo)
  for (int i = tid; i < 2048; i += 192) {
    int m = i >> 7, k4 = (i & 127) << 2;
    f32x4 v = *(const f32x4*)(h0 + (long)(bg * 16 + m) * HID + k4);
    short4_t sh, sl;
    #pragma unroll
    for (int c2 = 0; c2 < 4; c2++) {
      short hh = f2bf(v[c2]); sh[c2] = hh; sl[c2] = f2bf(v[c2] - bf2f(hh));
    }
    *(short4_t*)&h_hi[m][k4] = sh;
    *(short4_t*)&h_lo[m][k4] = sl;
  }
  __syncthreads();

  unsigned* my_bar = bar + bg * 32;  // 128B-spaced per-group counters

  #pragma unroll 1
  for (int t = 0; t < TT; t++) {
    // gh (this wave's gate, 16x16 tile): bf16x2 split, 3 independent acc chains
    f32x4 a0 = {0.f, 0.f, 0.f, 0.f}, a1 = a0, a2 = a0;
    #pragma unroll
    for (int ks = 0; ks < 16; ks++) {
      short8 ah = *(const short8*)&h_hi[n16][ks * 32 + quad * 8];
      short8 al = *(const short8*)&h_lo[n16][ks * 32 + quad * 8];
      a0 = __builtin_amdgcn_mfma_f32_16x16x32_bf16(ah, whi[ks], a0, 0, 0, 0);
      a1 = __builtin_amdgcn_mfma_f32_16x16x32_bf16(al, whi[ks], a1, 0, 0, 0);
      a2 = __builtin_amdgcn_mfma_f32_16x16x32_bf16(ah, wlo[ks], a2, 0, 0, 0);
    }
    #pragma unroll
    for (int r = 0; r < 4; r++)            // C layout: col=lane&15, row=quad*4+r
      gh_s[wv][quad * 4 + r][n16] = a0[r] + a1[r] + a2[r];
    __syncthreads();

    // elementwise gates + h update (gi computed inline from actions)
    for (int e = tid; e < 256; e += 192) {
      int m = e >> 4, n = e & 15;
      float hr = gh_s[0][m][n] + bhh_s[n];
      float hz = gh_s[1][m][n] + bhh_s[16 + n];
      float hn = gh_s[2][m][n] + bhh_s[32 + n];
      float x0 = act_s[m][2 * t], x1 = act_s[m][2 * t + 1];
      float ir = x0 * wih0_s[n]      + x1 * wih1_s[n]      + bih_s[n];
      float iz = x0 * wih0_s[16 + n] + x1 * wih1_s[16 + n] + bih_s[16 + n];
      float in_ = x0 * wih0_s[32 + n] + x1 * wih1_s[32 + n] + bih_s[32 + n];
      float rg = 1.f / (1.f + __expf(-(ir + hr)));
      float zg = 1.f / (1.f + __expf(-(iz + hz)));
      float nx = in_ + rg * hn;
      float ng = 1.f - 2.f / (__expf(2.f * nx) + 1.f);   // tanh
      float hprev = bf2f(h_hi[m][hg * 16 + n]) + bf2f(h_lo[m][hg * 16 + n]);
      float hy = ng + zg * (hprev - ng);
      out[((long)(bg * 16 + m) * TT + t) * HID + hg * 16 + n] = hy;
      if (t == TT - 1) hT[(long)(bg * 16 + m) * HID + hg * 16 + n] = hy;
    }
    __syncthreads();

    if (t < TT - 1) {
      if (tid == 0) {
        __threadfence();  // release: publish our h_t slice device-wide
        __hip_atomic_fetch_add(my_bar, 1u, __ATOMIC_RELEASE, __HIP_MEMORY_SCOPE_AGENT);
        const unsigned target = 32u * (unsigned)(t + 1);
        while (__hip_atomic_load(my_bar, __ATOMIC_ACQUIRE, __HIP_MEMORY_SCOPE_AGENT) < target)
          __builtin_amdgcn_s_sleep(2);
      }
      __syncthreads();
      __threadfence();    // acquire side for all threads before re-reading h
      // reload full h_t (16 rows x 512) from out -> LDS bf16 hi/lo
      for (int i = tid; i < 2048; i += 192) {
        int m = i >> 7, k4 = (i & 127) << 2;
        f32x4 v = *(const f32x4*)(out + ((long)(bg * 16 + m) * TT + t) * HID + k4);
        short4_t sh, sl;
        #pragma unroll
        for (int c2 = 0; c2 < 4; c2++) {
          short hh = f2bf(v[c2]); sh[c2] = hh; sl[c2] = f2bf(v[c2] - bf2f(hh));
        }
        *(short4_t*)&h_hi[m][k4] = sh;
        *(short4_t*)&h_lo[m][k4] = sl;
      }
      __syncthreads();
    }
  }
}

// ==================== launch ====================
extern "C" void kernel_launch(void* const* d_in, const int* in_sizes, int n_in,
                              void* d_out, int out_size, void* d_ws, size_t ws_size,
                              hipStream_t stream) {
  const float* images  = (const float*)d_in[0];
  const float* actions = (const float*)d_in[1];
  const float* cw1 = (const float*)d_in[2];
  const float* cb1 = (const float*)d_in[3];
  const float* cw2 = (const float*)d_in[4];
  const float* cb2 = (const float*)d_in[5];
  const float* cw3 = (const float*)d_in[6];
  const float* cb3 = (const float*)d_in[7];
  const float* fw1 = (const float*)d_in[8];
  const float* fb1 = (const float*)d_in[9];
  const float* fw2 = (const float*)d_in[10];
  const float* fb2 = (const float*)d_in[11];
  const float* fw3 = (const float*)d_in[12];
  const float* fb3 = (const float*)d_in[13];
  const float* w_ih = (const float*)d_in[14];
  const float* w_hh = (const float*)d_in[15];
  const float* b_ih = (const float*)d_in[16];
  const float* b_hh = (const float*)d_in[17];

  char* ws = (char*)d_ws;
  unsigned* bar = (unsigned*)ws;                 // 1 KB of barrier counters
  float* a1 = (float*)(ws + 1024);               // [128,64,24,24]
  float* a2 = a1 + (long)128 * 64 * 576;         // [128,64,9,9]
  float* a3 = a2 + (long)128 * 64 * 81;          // [128,1024] flat
  float* f1 = a3 + (long)128 * 1024;             // [128,1024]
  float* f2 = f1 + (long)128 * 1024;             // [128,512]
  float* h0 = f2 + (long)128 * 512;              // [128,512]

  float* out = (float*)d_out;                    // [128,100,512]
  float* hT  = out + (long)BB * TT * HID;        // [128,512]

  hipMemsetAsync(bar, 0, 1024, stream);
  conv1_k<<<18432, 256, 0, stream>>>(images, cw1, cb1, a1);
  convs3<64, 24, 24, 64, 9, 9><<<128 * 9, 576, 0, stream>>>(a1, cw2, cb2, a2);
  convs3<64, 9, 9, 64, 4, 4><<<128 * 4, 256, 0, stream>>>(a2, cw3, cb3, a3);
  fc_k<1024, 1024, true><<<64, 256, 0, stream>>>(a3, fw1, fb1, f1);
  fc_k<1024, 512, true><<<32, 256, 0, stream>>>(f1, fw2, fb2, f2);
  fc_k<512, 512, false><<<32, 256, 0, stream>>>(f2, fw3, fb3, h0);
  gru_k<<<256, 192, 0, stream>>>(actions, w_ih, w_hh, b_ih, b_hh, h0, out, hT, bar);
}

// Round 4
// 1590.519 us; speedup vs baseline: 1.9946x; 1.9946x over previous
//
#include <hip/hip_runtime.h>
#include <cstdint>

// ---------------- problem constants ----------------
#define BB   128
#define TT   100
#define HID  512

typedef __attribute__((ext_vector_type(4))) float f32x4;
typedef __attribute__((ext_vector_type(8))) short short8;
typedef __attribute__((ext_vector_type(4))) short short4_t;

__device__ __forceinline__ short f2bf(float x) {            // RNE fp32 -> bf16
  unsigned u = __float_as_uint(x);
  unsigned r = (u + 0x7fffu + ((u >> 16) & 1u)) >> 16;
  return (short)r;
}
__device__ __forceinline__ float bf2f(short s) {
  return __uint_as_float(((unsigned)(unsigned short)s) << 16);
}

// ==================== encoder ====================

// conv1: in [128,3,72,72], w [64,3,5,5], stride 3 pad 2 -> out [128,64,24,24], ReLU
__global__ __launch_bounds__(256) void conv1_k(const float* __restrict__ in,
                                               const float* __restrict__ w,
                                               const float* __restrict__ bias,
                                               float* __restrict__ out) {
  __shared__ float ws[64 * 75];
  for (int i = threadIdx.x; i < 64 * 75; i += 256) ws[i] = w[i];
  __syncthreads();
  int tid = blockIdx.x * 256 + threadIdx.x;          // exactly 128*64*576
  int ox = tid % 24, oy = (tid / 24) % 24, oc = (tid / 576) % 64, b = tid / 36864;
  const float* ip = in + (long)b * 3 * 5184;
  const float* wp = ws + oc * 75;
  float s = bias[oc];
  #pragma unroll
  for (int ic = 0; ic < 3; ic++)
    #pragma unroll
    for (int ky = 0; ky < 5; ky++) {
      int iy = oy * 3 + ky - 2;
      if (iy < 0 || iy >= 72) continue;
      #pragma unroll
      for (int kx = 0; kx < 5; kx++) {
        int ix = ox * 3 + kx - 2;
        if (ix < 0 || ix >= 72) continue;
        s += ip[ic * 5184 + iy * 72 + ix] * wp[ic * 25 + ky * 5 + kx];
      }
    }
  out[tid] = fmaxf(s, 0.f);
}

// 3x3 stride-3 pad-2 conv, ReLU. block = (b, oy); threads = OC*OW
template <int IC, int IH, int IW, int OC, int OH, int OW>
__global__ void convs3(const float* __restrict__ in, const float* __restrict__ w,
                       const float* __restrict__ bias, float* __restrict__ out) {
  const int b = blockIdx.x / OH, oy = blockIdx.x % OH;
  __shared__ float in_s[8][3][IW];
  __shared__ float w_s[OC][8][9];
  const int tid = threadIdx.x;
  const int oc = tid / OW, ox = tid % OW;
  float s = bias[oc];
  for (int cc = 0; cc < IC; cc += 8) {
    __syncthreads();
    for (int i = tid; i < 8 * 3 * IW; i += OC * OW) {
      int ic = i / (3 * IW), r = (i / IW) % 3, x = i % IW;
      int iy = oy * 3 - 2 + r;
      in_s[ic][r][x] = (iy >= 0 && iy < IH)
                         ? in[((long)(b * IC + cc + ic) * IH + iy) * IW + x] : 0.f;
    }
    for (int i = tid; i < OC * 8 * 9; i += OC * OW) {
      int o = i / 72, r = i % 72;
      w_s[o][r / 9][r % 9] = w[(long)(o * IC + cc + r / 9) * 9 + r % 9];
    }
    __syncthreads();
    #pragma unroll
    for (int ic = 0; ic < 8; ic++)
      #pragma unroll
      for (int ky = 0; ky < 3; ky++)
        #pragma unroll
        for (int kx = 0; kx < 3; kx++) {
          int ix = ox * 3 + kx - 2;
          if (ix >= 0 && ix < IW) s += in_s[ic][ky][ix] * w_s[oc][ic][ky * 3 + kx];
        }
  }
  out[((long)(b * OC + oc) * OH + oy) * OW + ox] = fmaxf(s, 0.f);
}

// C[128,N] = act(A[128,K] @ W[N,K]^T + b). tile 32x64, 256 thr, 8 rows/thread
template <int K, int N, bool RELU>
__global__ __launch_bounds__(256) void fc_k(const float* __restrict__ A,
                                            const float* __restrict__ W,
                                            const float* __restrict__ bias,
                                            float* __restrict__ C) {
  const int nb = N / 64;
  const int rb = (blockIdx.x / nb) * 32, cb = (blockIdx.x % nb) * 64;
  __shared__ float As[32][65];
  __shared__ float Ws[64][65];
  const int tid = threadIdx.x;
  const int c = tid & 63, rg = tid >> 6;
  float acc[8] = {0.f, 0.f, 0.f, 0.f, 0.f, 0.f, 0.f, 0.f};
  for (int kc = 0; kc < K; kc += 64) {
    for (int i = tid; i < 32 * 64; i += 256)
      As[i >> 6][i & 63] = A[(long)(rb + (i >> 6)) * K + kc + (i & 63)];
    for (int i = tid; i < 64 * 64; i += 256)
      Ws[i >> 6][i & 63] = W[(long)(cb + (i >> 6)) * K + kc + (i & 63)];
    __syncthreads();
    #pragma unroll 8
    for (int k = 0; k < 64; k++) {
      float wv = Ws[c][k];
      #pragma unroll
      for (int i = 0; i < 8; i++) acc[i] += As[rg + 4 * i][k] * wv;
    }
    __syncthreads();
  }
  float bv = bias[cb + c];
  #pragma unroll
  for (int i = 0; i < 8; i++) {
    float v = acc[i] + bv;
    if (RELU) v = fmaxf(v, 0.f);
    C[(long)(rb + rg + 4 * i) * N + cb + c] = v;
  }
}

// ==================== persistent GRU ====================
// grid 256 = 8 batch-groups (contiguous 32-block ranges) x 32 hidden-groups.
// block: 16 batch rows x 16 hidden dims, 192 threads = 3 waves (one per gate).
// w_hh slice held in registers as bf16 hi/lo MFMA B-fragments (bf16x2 split).
//
// h exchange between the 32 blocks of a group goes through d_out (time-indexed)
// using *relaxed* agent-scope atomics for BOTH data and the barrier counter.
// Agent-scope atomics bypass the non-coherent L1/L2 and operate at the
// coherent point (L3) directly, so NO buffer_inv / buffer_wbl2 cache
// maintenance is needed anywhere. (Round 0 used ACQUIRE polling = full L2
// invalidate per poll iteration = 25us/step. This removes all of that.)
// HW ordering: store->flag by __syncthreads' vmcnt(0) drain; flag->load by
// program order after s_barrier.
__global__ __launch_bounds__(192, 1) void gru_k(
    const float* __restrict__ actions, const float* __restrict__ w_ih,
    const float* __restrict__ w_hh, const float* __restrict__ b_ih,
    const float* __restrict__ b_hh, const float* __restrict__ h0,
    float* __restrict__ out, float* __restrict__ hT, unsigned* __restrict__ bar) {
  const int bg = blockIdx.x >> 5;   // 0..7
  const int hg = blockIdx.x & 31;   // 0..31
  const int tid = threadIdx.x;
  const int wv = tid >> 6;          // gate: 0=r 1=z 2=n
  const int lane = tid & 63;
  const int n16 = lane & 15;
  const int quad = lane >> 4;

  __shared__ short h_hi[16][520];   // +8 pad: 2-way-max LDS banking for b128 reads
  __shared__ short h_lo[16][520];
  __shared__ float act_s[16][2 * TT];
  __shared__ float gh_s[3][16][17];
  __shared__ float bih_s[48], bhh_s[48], wih0_s[48], wih1_s[48];

  // ---- per-lane w_hh B-fragments (resident in VGPRs for the whole kernel) ----
  short8 whi[16], wlo[16];
  {
    const int grow = wv * HID + hg * 16 + n16;
    const float* wr = w_hh + (long)grow * HID + quad * 8;
    #pragma unroll
    for (int ks = 0; ks < 16; ks++) {
      f32x4 v0 = *(const f32x4*)(wr + ks * 32);
      f32x4 v1 = *(const f32x4*)(wr + ks * 32 + 4);
      short8 hi, lo;
      #pragma unroll
      for (int j = 0; j < 4; j++) {
        short h1 = f2bf(v0[j]); hi[j] = h1;     lo[j] = f2bf(v0[j] - bf2f(h1));
        short h2 = f2bf(v1[j]); hi[j + 4] = h2; lo[j + 4] = f2bf(v1[j] - bf2f(h2));
      }
      whi[ks] = hi; wlo[ks] = lo;
    }
  }
  for (int i = tid; i < 48; i += 192) {
    int row = (i >> 4) * HID + hg * 16 + (i & 15);
    bih_s[i] = b_ih[row];
    bhh_s[i] = b_hh[row];
    wih0_s[i] = w_ih[row * 2];
    wih1_s[i] = w_ih[row * 2 + 1];
  }
  for (int i = tid; i < 16 * 2 * TT; i += 192) {
    int m = i / (2 * TT), r = i % (2 * TT);
    act_s[m][r] = actions[(long)(bg * 16 + m) * (2 * TT) + r];
  }
  // h0 -> LDS (bf16 hi/lo)
  for (int i = tid; i < 2048; i += 192) {
    int m = i >> 7, k4 = (i & 127) << 2;
    f32x4 v = *(const f32x4*)(h0 + (long)(bg * 16 + m) * HID + k4);
    short4_t sh, sl;
    #pragma unroll
    for (int c2 = 0; c2 < 4; c2++) {
      short hh = f2bf(v[c2]); sh[c2] = hh; sl[c2] = f2bf(v[c2] - bf2f(hh));
    }
    *(short4_t*)&h_hi[m][k4] = sh;
    *(short4_t*)&h_lo[m][k4] = sl;
  }
  __syncthreads();

  unsigned* my_bar = bar + bg * 32;  // 128B-spaced per-group counters

  #pragma unroll 1
  for (int t = 0; t < TT; t++) {
    // gh (this wave's gate, 16x16 tile): bf16x2 split, 3 independent acc chains
    f32x4 a0 = {0.f, 0.f, 0.f, 0.f}, a1 = a0, a2 = a0;
    #pragma unroll
    for (int ks = 0; ks < 16; ks++) {
      short8 ah = *(const short8*)&h_hi[n16][ks * 32 + quad * 8];
      short8 al = *(const short8*)&h_lo[n16][ks * 32 + quad * 8];
      a0 = __builtin_amdgcn_mfma_f32_16x16x32_bf16(ah, whi[ks], a0, 0, 0, 0);
      a1 = __builtin_amdgcn_mfma_f32_16x16x32_bf16(al, whi[ks], a1, 0, 0, 0);
      a2 = __builtin_amdgcn_mfma_f32_16x16x32_bf16(ah, wlo[ks], a2, 0, 0, 0);
    }
    #pragma unroll
    for (int r = 0; r < 4; r++)            // C layout: col=lane&15, row=quad*4+r
      gh_s[wv][quad * 4 + r][n16] = a0[r] + a1[r] + a2[r];
    __syncthreads();

    // elementwise gates + h update (gi computed inline from actions)
    for (int e = tid; e < 256; e += 192) {
      int m = e >> 4, n = e & 15;
      float hr = gh_s[0][m][n] + bhh_s[n];
      float hz = gh_s[1][m][n] + bhh_s[16 + n];
      float hn = gh_s[2][m][n] + bhh_s[32 + n];
      float x0 = act_s[m][2 * t], x1 = act_s[m][2 * t + 1];
      float ir = x0 * wih0_s[n]      + x1 * wih1_s[n]      + bih_s[n];
      float iz = x0 * wih0_s[16 + n] + x1 * wih1_s[16 + n] + bih_s[16 + n];
      float in_ = x0 * wih0_s[32 + n] + x1 * wih1_s[32 + n] + bih_s[32 + n];
      float rg = 1.f / (1.f + __expf(-(ir + hr)));
      float zg = 1.f / (1.f + __expf(-(iz + hz)));
      float nx = in_ + rg * hn;
      float ng = 1.f - 2.f / (__expf(2.f * nx) + 1.f);   // tanh
      float hprev = bf2f(h_hi[m][hg * 16 + n]) + bf2f(h_lo[m][hg * 16 + n]);
      float hy = ng + zg * (hprev - ng);
      // device-coherent store (bypasses non-coherent L1/L2; no cache maint.)
      __hip_atomic_store(&out[((long)(bg * 16 + m) * TT + t) * HID + hg * 16 + n],
                         hy, __ATOMIC_RELAXED, __HIP_MEMORY_SCOPE_AGENT);
      if (t == TT - 1) hT[(long)(bg * 16 + m) * HID + hg * 16 + n] = hy;
    }
    __syncthreads();   // drains vmcnt(0): slice stores are device-visible

    if (t < TT - 1) {
      if (tid == 0) {
        const unsigned target = 32u * (unsigned)(t + 1);
        unsigned prev = __hip_atomic_fetch_add(my_bar, 1u, __ATOMIC_RELAXED,
                                               __HIP_MEMORY_SCOPE_AGENT);
        if (prev + 1u < target) {
          while (__hip_atomic_load(my_bar, __ATOMIC_RELAXED,
                                   __HIP_MEMORY_SCOPE_AGENT) < target)
            __builtin_amdgcn_s_sleep(1);
        }
      }
      __syncthreads();
      // reload full h_t (16 rows x 512) via coherent 8B loads -> LDS bf16 hi/lo
      for (int i = tid; i < 4096; i += 192) {
        int m = i >> 8, j = (i & 255) << 1;
        unsigned long long v = __hip_atomic_load(
            (const unsigned long long*)(out + ((long)(bg * 16 + m) * TT + t) * HID + j),
            __ATOMIC_RELAXED, __HIP_MEMORY_SCOPE_AGENT);
        float f0 = __uint_as_float((unsigned)v);
        float f1 = __uint_as_float((unsigned)(v >> 32));
        short s0 = f2bf(f0);
        h_hi[m][j] = s0; h_lo[m][j] = f2bf(f0 - bf2f(s0));
        short s1 = f2bf(f1);
        h_hi[m][j + 1] = s1; h_lo[m][j + 1] = f2bf(f1 - bf2f(s1));
      }
      __syncthreads();
    }
  }
}

// ==================== launch ====================
extern "C" void kernel_launch(void* const* d_in, const int* in_sizes, int n_in,
                              void* d_out, int out_size, void* d_ws, size_t ws_size,
                              hipStream_t stream) {
  const float* images  = (const float*)d_in[0];
  const float* actions = (const float*)d_in[1];
  const float* cw1 = (const float*)d_in[2];
  const float* cb1 = (const float*)d_in[3];
  const float* cw2 = (const float*)d_in[4];
  const float* cb2 = (const float*)d_in[5];
  const float* cw3 = (const float*)d_in[6];
  const float* cb3 = (const float*)d_in[7];
  const float* fw1 = (const float*)d_in[8];
  const float* fb1 = (const float*)d_in[9];
  const float* fw2 = (const float*)d_in[10];
  const float* fb2 = (const float*)d_in[11];
  const float* fw3 = (const float*)d_in[12];
  const float* fb3 = (const float*)d_in[13];
  const float* w_ih = (const float*)d_in[14];
  const float* w_hh = (const float*)d_in[15];
  const float* b_ih = (const float*)d_in[16];
  const float* b_hh = (const float*)d_in[17];

  char* ws = (char*)d_ws;
  unsigned* bar = (unsigned*)ws;                 // 1 KB of barrier counters
  float* a1 = (float*)(ws + 1024);               // [128,64,24,24]
  float* a2 = a1 + (long)128 * 64 * 576;         // [128,64,9,9]
  float* a3 = a2 + (long)128 * 64 * 81;          // [128,1024] flat
  float* f1 = a3 + (long)128 * 1024;             // [128,1024]
  float* f2 = f1 + (long)128 * 1024;             // [128,512]
  float* h0 = f2 + (long)128 * 512;              // [128,512]

  float* out = (float*)d_out;                    // [128,100,512]
  float* hT  = out + (long)BB * TT * HID;        // [128,512]

  hipMemsetAsync(bar, 0, 1024, stream);
  conv1_k<<<18432, 256, 0, stream>>>(images, cw1, cb1, a1);
  convs3<64, 24, 24, 64, 9, 9><<<128 * 9, 576, 0, stream>>>(a1, cw2, cb2, a2);
  convs3<64, 9, 9, 64, 4, 4><<<128 * 4, 256, 0, stream>>>(a2, cw3, cb3, a3);
  fc_k<1024, 1024, true><<<64, 256, 0, stream>>>(a3, fw1, fb1, f1);
  fc_k<1024, 512, true><<<32, 256, 0, stream>>>(f1, fw2, fb2, f2);
  fc_k<512, 512, false><<<32, 256, 0, stream>>>(f2, fw3, fb3, h0);
  gru_k<<<256, 192, 0, stream>>>(actions, w_ih, w_hh, b_ih, b_hh, h0, out, hT, bar);
}

// Round 5
// 1017.952 us; speedup vs baseline: 3.1165x; 1.5625x over previous
//
#include <hip/hip_runtime.h>
#include <cstdint>

// ---------------- problem constants ----------------
#define BB   128
#define TT   100
#define HID  512

typedef __attribute__((ext_vector_type(4))) float f32x4;
typedef __attribute__((ext_vector_type(8))) short short8;
typedef __attribute__((ext_vector_type(4))) short short4_t;

__device__ __forceinline__ short f2bf(float x) {            // RNE fp32 -> bf16
  unsigned u = __float_as_uint(x);
  unsigned r = (u + 0x7fffu + ((u >> 16) & 1u)) >> 16;
  return (short)r;
}
__device__ __forceinline__ float bf2f(short s) {
  return __uint_as_float(((unsigned)(unsigned short)s) << 16);
}

// ==================== encoder ====================

// conv1: in [128,3,72,72], w [64,3,5,5], stride 3 pad 2 -> out [128,64,24,24], ReLU
__global__ __launch_bounds__(256) void conv1_k(const float* __restrict__ in,
                                               const float* __restrict__ w,
                                               const float* __restrict__ bias,
                                               float* __restrict__ out) {
  __shared__ float ws[64 * 75];
  for (int i = threadIdx.x; i < 64 * 75; i += 256) ws[i] = w[i];
  __syncthreads();
  int tid = blockIdx.x * 256 + threadIdx.x;          // exactly 128*64*576
  int ox = tid % 24, oy = (tid / 24) % 24, oc = (tid / 576) % 64, b = tid / 36864;
  const float* ip = in + (long)b * 3 * 5184;
  const float* wp = ws + oc * 75;
  float s = bias[oc];
  #pragma unroll
  for (int ic = 0; ic < 3; ic++)
    #pragma unroll
    for (int ky = 0; ky < 5; ky++) {
      int iy = oy * 3 + ky - 2;
      if (iy < 0 || iy >= 72) continue;
      #pragma unroll
      for (int kx = 0; kx < 5; kx++) {
        int ix = ox * 3 + kx - 2;
        if (ix < 0 || ix >= 72) continue;
        s += ip[ic * 5184 + iy * 72 + ix] * wp[ic * 25 + ky * 5 + kx];
      }
    }
  out[tid] = fmaxf(s, 0.f);
}

// 3x3 stride-3 pad-2 conv, ReLU. block = (b, oy); threads = OC*OW.
// Input staged into LDS with halo padding (p = ix+2) -> branch-free inner loop.
template <int IC, int IH, int IW, int OC, int OH, int OW>
__global__ void convs3(const float* __restrict__ in, const float* __restrict__ w,
                       const float* __restrict__ bias, float* __restrict__ out) {
  const int b = blockIdx.x / OH, oy = blockIdx.x % OH;
  constexpr int PW = 3 * OW;           // padded width; p = ox*3+kx in [0, 3*OW-1]
  __shared__ float in_s[8][3][PW];
  __shared__ float w_s[OC][8][9];
  const int tid = threadIdx.x;
  const int oc = tid / OW, ox = tid % OW;
  float s = bias[oc];
  for (int cc = 0; cc < IC; cc += 8) {
    __syncthreads();
    for (int i = tid; i < 8 * 3 * PW; i += OC * OW) {
      int ic = i / (3 * PW), r = (i / PW) % 3, p = i % PW;
      int iy = oy * 3 - 2 + r, ix = p - 2;
      in_s[ic][r][p] = (iy >= 0 && iy < IH && ix >= 0 && ix < IW)
                         ? in[((long)(b * IC + cc + ic) * IH + iy) * IW + ix] : 0.f;
    }
    for (int i = tid; i < OC * 8 * 9; i += OC * OW) {
      int o = i / 72, r = i % 72;
      w_s[o][r / 9][r % 9] = w[(long)(o * IC + cc + r / 9) * 9 + r % 9];
    }
    __syncthreads();
    #pragma unroll
    for (int ic = 0; ic < 8; ic++)
      #pragma unroll
      for (int ky = 0; ky < 3; ky++)
        #pragma unroll
        for (int kx = 0; kx < 3; kx++)
          s += in_s[ic][ky][ox * 3 + kx] * w_s[oc][ic][ky * 3 + kx];
  }
  out[((long)(b * OC + oc) * OH + oy) * OW + ox] = fmaxf(s, 0.f);
}

// C[128,N] = act(A[128,K] @ W[N,K]^T + b). tile 32x64, 256 thr, 8 rows/thread
template <int K, int N, bool RELU>
__global__ __launch_bounds__(256) void fc_k(const float* __restrict__ A,
                                            const float* __restrict__ W,
                                            const float* __restrict__ bias,
                                            float* __restrict__ C) {
  const int nb = N / 64;
  const int rb = (blockIdx.x / nb) * 32, cb = (blockIdx.x % nb) * 64;
  __shared__ float As[32][65];
  __shared__ float Ws[64][65];
  const int tid = threadIdx.x;
  const int c = tid & 63, rg = tid >> 6;
  float acc[8] = {0.f, 0.f, 0.f, 0.f, 0.f, 0.f, 0.f, 0.f};
  for (int kc = 0; kc < K; kc += 64) {
    for (int i = tid; i < 32 * 64; i += 256)
      As[i >> 6][i & 63] = A[(long)(rb + (i >> 6)) * K + kc + (i & 63)];
    for (int i = tid; i < 64 * 64; i += 256)
      Ws[i >> 6][i & 63] = W[(long)(cb + (i >> 6)) * K + kc + (i & 63)];
    __syncthreads();
    #pragma unroll 8
    for (int k = 0; k < 64; k++) {
      float wv = Ws[c][k];
      #pragma unroll
      for (int i = 0; i < 8; i++) acc[i] += As[rg + 4 * i][k] * wv;
    }
    __syncthreads();
  }
  float bv = bias[cb + c];
  #pragma unroll
  for (int i = 0; i < 8; i++) {
    float v = acc[i] + bv;
    if (RELU) v = fmaxf(v, 0.f);
    C[(long)(rb + rg + 4 * i) * N + cb + c] = v;
  }
}

// ==================== persistent GRU ====================
// grid 256 = 8 batch-groups (contiguous 32-block ranges) x 32 hidden-groups.
// block: 16 batch rows x 16 hidden dims, 192 threads = 3 waves (one per gate).
// w_hh slice held in registers as bf16 hi/lo MFMA B-fragments (bf16x2 split).
//
// h exchange through d_out (time-indexed) with *relaxed* agent-scope atomics
// for data + barrier (coherent-point access, zero cache maintenance).
// R4 post-mortem: reload loop was rolled -> one L3 round trip per 8B load
// (~21 x 900cy = 8us/step). Now software-pipelined: fully-unrolled load phase
// into a 22-slot register buffer, then a separate convert/LDS phase.
__global__ __launch_bounds__(192, 1) void gru_k(
    const float* __restrict__ actions, const float* __restrict__ w_ih,
    const float* __restrict__ w_hh, const float* __restrict__ b_ih,
    const float* __restrict__ b_hh, const float* __restrict__ h0,
    float* __restrict__ out, float* __restrict__ hT, unsigned* __restrict__ bar) {
  const int bg = blockIdx.x >> 5;   // 0..7
  const int hg = blockIdx.x & 31;   // 0..31
  const int tid = threadIdx.x;
  const int wv = tid >> 6;          // gate: 0=r 1=z 2=n
  const int lane = tid & 63;
  const int n16 = lane & 15;
  const int quad = lane >> 4;

  __shared__ short h_hi[16][520];   // +8 pad: 2-way-max LDS banking for b128 reads
  __shared__ short h_lo[16][520];
  __shared__ float act_s[16][2 * TT];
  __shared__ float gh_s[3][16][17];
  __shared__ float bih_s[48], bhh_s[48], wih0_s[48], wih1_s[48];

  // ---- per-lane w_hh B-fragments (resident in VGPRs for the whole kernel) ----
  short8 whi[16], wlo[16];
  {
    const int grow = wv * HID + hg * 16 + n16;
    const float* wr = w_hh + (long)grow * HID + quad * 8;
    #pragma unroll
    for (int ks = 0; ks < 16; ks++) {
      f32x4 v0 = *(const f32x4*)(wr + ks * 32);
      f32x4 v1 = *(const f32x4*)(wr + ks * 32 + 4);
      short8 hi, lo;
      #pragma unroll
      for (int j = 0; j < 4; j++) {
        short h1 = f2bf(v0[j]); hi[j] = h1;     lo[j] = f2bf(v0[j] - bf2f(h1));
        short h2 = f2bf(v1[j]); hi[j + 4] = h2; lo[j + 4] = f2bf(v1[j] - bf2f(h2));
      }
      whi[ks] = hi; wlo[ks] = lo;
    }
  }
  for (int i = tid; i < 48; i += 192) {
    int row = (i >> 4) * HID + hg * 16 + (i & 15);
    bih_s[i] = b_ih[row];
    bhh_s[i] = b_hh[row];
    wih0_s[i] = w_ih[row * 2];
    wih1_s[i] = w_ih[row * 2 + 1];
  }
  for (int i = tid; i < 16 * 2 * TT; i += 192) {
    int m = i / (2 * TT), r = i % (2 * TT);
    act_s[m][r] = actions[(long)(bg * 16 + m) * (2 * TT) + r];
  }
  // h0 -> LDS (bf16 hi/lo)
  for (int i = tid; i < 2048; i += 192) {
    int m = i >> 7, k4 = (i & 127) << 2;
    f32x4 v = *(const f32x4*)(h0 + (long)(bg * 16 + m) * HID + k4);
    short4_t sh, sl;
    #pragma unroll
    for (int c2 = 0; c2 < 4; c2++) {
      short hh = f2bf(v[c2]); sh[c2] = hh; sl[c2] = f2bf(v[c2] - bf2f(hh));
    }
    *(short4_t*)&h_hi[m][k4] = sh;
    *(short4_t*)&h_lo[m][k4] = sl;
  }
  __syncthreads();

  unsigned* my_bar = bar + bg * 32;  // 128B-spaced per-group counters

  #pragma unroll 1
  for (int t = 0; t < TT; t++) {
    // gh (this wave's gate, 16x16 tile): bf16x2 split, 3 independent acc chains
    f32x4 a0 = {0.f, 0.f, 0.f, 0.f}, a1 = a0, a2 = a0;
    #pragma unroll
    for (int ks = 0; ks < 16; ks++) {
      short8 ah = *(const short8*)&h_hi[n16][ks * 32 + quad * 8];
      short8 al = *(const short8*)&h_lo[n16][ks * 32 + quad * 8];
      a0 = __builtin_amdgcn_mfma_f32_16x16x32_bf16(ah, whi[ks], a0, 0, 0, 0);
      a1 = __builtin_amdgcn_mfma_f32_16x16x32_bf16(al, whi[ks], a1, 0, 0, 0);
      a2 = __builtin_amdgcn_mfma_f32_16x16x32_bf16(ah, wlo[ks], a2, 0, 0, 0);
    }
    #pragma unroll
    for (int r = 0; r < 4; r++)            // C layout: col=lane&15, row=quad*4+r
      gh_s[wv][quad * 4 + r][n16] = a0[r] + a1[r] + a2[r];
    __syncthreads();

    // elementwise gates + h update; 128 threads x 2 hidden dims, 8B packed store
    if (tid < 128) {
      const int m = tid >> 3;
      const int n0 = (tid & 7) << 1;
      const float x0 = act_s[m][2 * t], x1 = act_s[m][2 * t + 1];
      float hy[2];
      #pragma unroll
      for (int q = 0; q < 2; q++) {
        int n = n0 + q;
        float hr = gh_s[0][m][n] + bhh_s[n];
        float hz = gh_s[1][m][n] + bhh_s[16 + n];
        float hn = gh_s[2][m][n] + bhh_s[32 + n];
        float ir = x0 * wih0_s[n]      + x1 * wih1_s[n]      + bih_s[n];
        float iz = x0 * wih0_s[16 + n] + x1 * wih1_s[16 + n] + bih_s[16 + n];
        float in_ = x0 * wih0_s[32 + n] + x1 * wih1_s[32 + n] + bih_s[32 + n];
        float rg = 1.f / (1.f + __expf(-(ir + hr)));
        float zg = 1.f / (1.f + __expf(-(iz + hz)));
        float nx = in_ + rg * hn;
        float ng = 1.f - 2.f / (__expf(2.f * nx) + 1.f);   // tanh
        float hprev = bf2f(h_hi[m][hg * 16 + n]) + bf2f(h_lo[m][hg * 16 + n]);
        hy[q] = ng + zg * (hprev - ng);
      }
      unsigned long long pack = (unsigned long long)__float_as_uint(hy[0]) |
                                ((unsigned long long)__float_as_uint(hy[1]) << 32);
      // device-coherent packed store (bypasses non-coherent L1/L2)
      __hip_atomic_store(
          (unsigned long long*)&out[((long)(bg * 16 + m) * TT + t) * HID + hg * 16 + n0],
          pack, __ATOMIC_RELAXED, __HIP_MEMORY_SCOPE_AGENT);
      if (t == TT - 1)
        *(unsigned long long*)&hT[(long)(bg * 16 + m) * HID + hg * 16 + n0] = pack;
    }
    __syncthreads();   // drains vmcnt(0): slice stores are device-visible

    if (t < TT - 1) {
      if (tid == 0) {
        const unsigned target = 32u * (unsigned)(t + 1);
        unsigned prev = __hip_atomic_fetch_add(my_bar, 1u, __ATOMIC_RELAXED,
                                               __HIP_MEMORY_SCOPE_AGENT);
        if (prev + 1u < target) {
          while (__hip_atomic_load(my_bar, __ATOMIC_RELAXED,
                                   __HIP_MEMORY_SCOPE_AGENT) < target)
            __builtin_amdgcn_s_sleep(1);
        }
      }
      __syncthreads();
      // ---- pipelined reload: 21 uniform 8B loads/thread + wave-0 tail ----
      // (4096 8B-chunks = 16 rows x 256; issue ALL loads, then convert)
      unsigned long long vbuf[22];
      #pragma unroll
      for (int u = 0; u < 21; u++) {
        int i = tid + u * 192;
        int m = i >> 8, j = (i & 255) << 1;
        vbuf[u] = __hip_atomic_load(
            (const unsigned long long*)(out + ((long)(bg * 16 + m) * TT + t) * HID + j),
            __ATOMIC_RELAXED, __HIP_MEMORY_SCOPE_AGENT);
      }
      if (tid < 64) {
        int i = 4032 + tid;
        int m = i >> 8, j = (i & 255) << 1;
        vbuf[21] = __hip_atomic_load(
            (const unsigned long long*)(out + ((long)(bg * 16 + m) * TT + t) * HID + j),
            __ATOMIC_RELAXED, __HIP_MEMORY_SCOPE_AGENT);
      }
      #pragma unroll
      for (int u = 0; u < 21; u++) {
        int i = tid + u * 192;
        int m = i >> 8, j = (i & 255) << 1;
        unsigned long long v = vbuf[u];
        float f0 = __uint_as_float((unsigned)v);
        float f1 = __uint_as_float((unsigned)(v >> 32));
        short s0 = f2bf(f0);
        h_hi[m][j] = s0; h_lo[m][j] = f2bf(f0 - bf2f(s0));
        short s1 = f2bf(f1);
        h_hi[m][j + 1] = s1; h_lo[m][j + 1] = f2bf(f1 - bf2f(s1));
      }
      if (tid < 64) {
        int i = 4032 + tid;
        int m = i >> 8, j = (i & 255) << 1;
        unsigned long long v = vbuf[21];
        float f0 = __uint_as_float((unsigned)v);
        float f1 = __uint_as_float((unsigned)(v >> 32));
        short s0 = f2bf(f0);
        h_hi[m][j] = s0; h_lo[m][j] = f2bf(f0 - bf2f(s0));
        short s1 = f2bf(f1);
        h_hi[m][j + 1] = s1; h_lo[m][j + 1] = f2bf(f1 - bf2f(s1));
      }
      __syncthreads();
    }
  }
}

// ==================== launch ====================
extern "C" void kernel_launch(void* const* d_in, const int* in_sizes, int n_in,
                              void* d_out, int out_size, void* d_ws, size_t ws_size,
                              hipStream_t stream) {
  const float* images  = (const float*)d_in[0];
  const float* actions = (const float*)d_in[1];
  const float* cw1 = (const float*)d_in[2];
  const float* cb1 = (const float*)d_in[3];
  const float* cw2 = (const float*)d_in[4];
  const float* cb2 = (const float*)d_in[5];
  const float* cw3 = (const float*)d_in[6];
  const float* cb3 = (const float*)d_in[7];
  const float* fw1 = (const float*)d_in[8];
  const float* fb1 = (const float*)d_in[9];
  const float* fw2 = (const float*)d_in[10];
  const float* fb2 = (const float*)d_in[11];
  const float* fw3 = (const float*)d_in[12];
  const float* fb3 = (const float*)d_in[13];
  const float* w_ih = (const float*)d_in[14];
  const float* w_hh = (const float*)d_in[15];
  const float* b_ih = (const float*)d_in[16];
  const float* b_hh = (const float*)d_in[17];

  char* ws = (char*)d_ws;
  unsigned* bar = (unsigned*)ws;                 // 1 KB of barrier counters
  float* a1 = (float*)(ws + 1024);               // [128,64,24,24]
  float* a2 = a1 + (long)128 * 64 * 576;         // [128,64,9,9]
  float* a3 = a2 + (long)128 * 64 * 81;          // [128,1024] flat
  float* f1 = a3 + (long)128 * 1024;             // [128,1024]
  float* f2 = f1 + (long)128 * 1024;             // [128,512]
  float* h0 = f2 + (long)128 * 512;              // [128,512]

  float* out = (float*)d_out;                    // [128,100,512]
  float* hT  = out + (long)BB * TT * HID;        // [128,512]

  hipMemsetAsync(bar, 0, 1024, stream);
  conv1_k<<<18432, 256, 0, stream>>>(images, cw1, cb1, a1);
  convs3<64, 24, 24, 64, 9, 9><<<128 * 9, 576, 0, stream>>>(a1, cw2, cb2, a2);
  convs3<64, 9, 9, 64, 4, 4><<<128 * 4, 256, 0, stream>>>(a2, cw3, cb3, a3);
  fc_k<1024, 1024, true><<<64, 256, 0, stream>>>(a3, fw1, fb1, f1);
  fc_k<1024, 512, true><<<32, 256, 0, stream>>>(f1, fw2, fb2, f2);
  fc_k<512, 512, false><<<32, 256, 0, stream>>>(f2, fw3, fb3, h0);
  gru_k<<<256, 192, 0, stream>>>(actions, w_ih, w_hh, b_ih, b_hh, h0, out, hT, bar);
}